// Round 1
// 186.441 us; speedup vs baseline: 1.0684x; 1.0684x over previous
//
#include <hip/hip_runtime.h>
#include <hip/hip_bf16.h>

// NSA forward, MI355X round 11. All inputs fp32, output fp32.
// r10 + attn_k rewrite: (1) swapped QK^T (mfma(K,Q)) -> lane-local softmax
// (2 shfl instead of 32/phase), (2) double-buffered async global_load_lds
// staging with XOR-swizzle baked into prep_k's Kb/VT layout (linear LDS dest,
// pre-swizzled source, swizzled ds_read), (3) one barrier per phase,
// (4) P written as packed b64. LDS 73 KB -> 2 blocks/CU.
// Shapes: S=4096, seqlen=2048, qh=8, kvh=2, dim=128, blk=64, TOPK=16,
// window=(512,0).

#define SEQ   2048
#define NB    2
#define KV    2
#define NH    4
#define QH    8
#define DIM   128
#define NBLK  32
#define NQB   32
#define NTOP  16
#define SCALE 0.08838834764831845f   // 128^-0.5
#define QS    36                     // cmp LDS quarter stride (floats)
#define RS    144                    // cmp LDS row stride
#define VP    72                     // P/prep-T LDS row stride (bf16): pad 8

typedef unsigned short ushort_t;
using bf16x8 = __attribute__((ext_vector_type(8))) short;
using f32x4  = __attribute__((ext_vector_type(4))) float;

__device__ __forceinline__ unsigned pkbf(float a, float b){
  union { __hip_bfloat162 h; unsigned u; } cv;
  cv.h = __float22bfloat162_rn(make_float2(a, b));
  return cv.u;
}

// async 16B direct-to-LDS copy (per-lane global src, wave-uniform LDS base)
__device__ __forceinline__ void async16(ushort_t* l, const ushort_t* g){
  __builtin_amdgcn_global_load_lds(
      (const __attribute__((address_space(1))) unsigned int*)(size_t)g,
      (__attribute__((address_space(3))) unsigned int*)(size_t)l,
      16, 0, 0);
}

// ---------------- kernel 0: K/V bf16 preprocessing --------------------------
// Kb row-major [bbg][row][128] bf16, each 256B row stored XOR-swizzled:
// byte ^= (row&7)<<4.  VT transposed [bbg][d][SEQ] bf16; within each 128B
// (64-seq) tile: byte ^= (d&7)<<4.  attn_k's global_load_lds then lands a
// swizzled LDS tile from a LINEAR copy; ds_reads apply the same XOR.
__global__ __launch_bounds__(256) void prep_k(
    const float* __restrict__ k, const float* __restrict__ v,
    ushort_t* __restrict__ Kb, ushort_t* __restrict__ VT)
{
  int blk = blockIdx.x;
  int db = blk & 1, rb = (blk >> 1) & 31, bbg = blk >> 6;
  int bb = bbg >> 1, g = bbg & 1;
  int tid = threadIdx.x;
  __shared__ ushort_t T[64*VP];    // [d 0..63][key 0..63], pad 8

  for (int jj = 0; jj < 4; ++jj){
    int i = tid + jj*256;                 // 1024 float4 units (64 rows x 16)
    int r = i >> 4, ds = i & 15;
    size_t src = ((size_t)(bb*SEQ + rb*64 + r)*KV + g)*DIM + db*64 + ds*4;
    float4 kx = *(const float4*)(k + src);
    float4 vx = *(const float4*)(v + src);
    uint2 kk; kk.x = pkbf(kx.x,kx.y); kk.y = pkbf(kx.z,kx.w);
    size_t rowb = ((size_t)bbg*SEQ + rb*64 + r)*DIM*2;        // row base bytes
    int swz = (db*128 + ds*8) ^ ((r & 7) << 4);               // within-row
    *(uint2*)((char*)Kb + rowb + swz) = kk;
    unsigned v01 = pkbf(vx.x,vx.y), v23 = pkbf(vx.z,vx.w);
    T[(ds*4+0)*VP + r] = (ushort_t)(v01 & 0xffffu);
    T[(ds*4+1)*VP + r] = (ushort_t)(v01 >> 16);
    T[(ds*4+2)*VP + r] = (ushort_t)(v23 & 0xffffu);
    T[(ds*4+3)*VP + r] = (ushort_t)(v23 >> 16);
  }
  __syncthreads();
  for (int jj = 0; jj < 4; ++jj){
    int i = tid + jj*256;                 // 1024 8B units (64 d x 16)
    int d = i >> 4, seg = i & 15;
    uint2 u = *(uint2*)&T[d*VP + seg*4];
    size_t rowb = ((size_t)bbg*DIM + db*64 + d)*SEQ*2;        // d-row bytes
    int swz = (seg*8) ^ ((d & 7) << 4);                       // within 128B tile
    *(uint2*)((char*)VT + rowb + rb*128 + swz) = u;
  }
}

// ---------------- kernel 1: block compression (fp32 out to ws) --------------
__global__ __launch_bounds__(256) void compress_k(
    const float* __restrict__ k, const float* __restrict__ v,
    const float* __restrict__ w_k, const float* __restrict__ b_k,
    const float* __restrict__ w_v, const float* __restrict__ b_v,
    float* __restrict__ Kc, float* __restrict__ Vc)
{
  int blk = blockIdx.x;            // (bb,g,n,dhalf)
  int dh = blk & 1;
  int n  = (blk >> 1) & 31;
  int g  = (blk >> 6) & 1;
  int bb = blk >> 7;
  int tid = threadIdx.x;

  __shared__ float wks[64], wvs[64];
  __shared__ float accK[16][64], accV[16][64];
  if (tid < 64){ wks[tid] = w_k[tid]; wvs[tid] = w_v[tid]; }
  __syncthreads();

  int r4 = tid >> 4, dq = tid & 15;
  float4 sk = {0,0,0,0}, sv = {0,0,0,0};
  for (int rr = 0; rr < 4; ++rr){
    int row = r4*4 + rr;
    size_t off = ((size_t)(bb*SEQ + n*64 + row)*KV + g)*DIM + dh*64 + dq*4;
    float4 kx = *(const float4*)(k + off);
    float4 vx = *(const float4*)(v + off);
    float a = wks[row], b = wvs[row];
    sk.x += a*kx.x; sk.y += a*kx.y; sk.z += a*kx.z; sk.w += a*kx.w;
    sv.x += b*vx.x; sv.y += b*vx.y; sv.z += b*vx.z; sv.w += b*vx.w;
  }
  *(float4*)&accK[r4][dq*4] = sk;
  *(float4*)&accV[r4][dq*4] = sv;
  __syncthreads();
  size_t obase = ((size_t)((bb*KV+g)*NBLK + n))*DIM + dh*64;
  if (tid < 64){
    float s = 0.f;
#pragma unroll
    for (int i = 0; i < 16; ++i) s += accK[i][tid];
    Kc[obase + tid] = s + b_k[0];
  } else if (tid < 128){
    int d = tid - 64;
    float s = 0.f;
#pragma unroll
    for (int i = 0; i < 16; ++i) s += accV[i][d];
    Vc[obase + d] = s + b_v[0];
  }
}

// ------- kernel 2: compressed attention (fp32 VALU; exact pooled P) ---------
__global__ __launch_bounds__(256) void cmp_attn_k(
    const float* __restrict__ q, const float* __restrict__ Kc,
    const float* __restrict__ Vc,
    const float* __restrict__ w_gate, const float* __restrict__ b_gate,
    float* __restrict__ pooled_part, float* __restrict__ out)
{
  int blk = blockIdx.x;
  int h  = blk & 3;
  int qb = (blk >> 2) & (NQB-1);
  int g  = (blk >> 7) & 1;
  int bb = blk >> 8;
  int tid = threadIdx.x;
  int qi = tid >> 2, c = tid & 3;

  __shared__ float Ks[32*RS];
  __shared__ float Vs[32*RS];
  __shared__ float wsum[4][NBLK];

  const float4* Ksrc = (const float4*)(Kc + (size_t)(bb*KV + g) * NBLK * DIM);
  const float4* Vsrc = (const float4*)(Vc + (size_t)(bb*KV + g) * NBLK * DIM);
  for (int i = tid; i < 1024; i += 256){
    int row = i >> 5, seg = i & 31;
    int dst = row*RS + (seg>>3)*QS + (seg&7)*4;
    ((float4*)(Ks+dst))[0] = Ksrc[i];
    ((float4*)(Vs+dst))[0] = Vsrc[i];
  }
  __syncthreads();

  int row = bb*SEQ + qb*64 + qi;
  float qv[32];
  {
    const float4* q4 = (const float4*)(q + ((size_t)row*QH + g*NH + h)*DIM + c*32);
#pragma unroll
    for (int j = 0; j < 8; ++j){
      float4 u = q4[j];
      qv[4*j+0]=u.x; qv[4*j+1]=u.y; qv[4*j+2]=u.z; qv[4*j+3]=u.w;
    }
  }

  float gp = 0.f;
#pragma unroll
  for (int d = 0; d < 32; ++d) gp += qv[d]*w_gate[(c*32+d)*3 + 0];
  gp += __shfl_xor(gp, 1); gp += __shfl_xor(gp, 2);
  float g0 = 1.f/(1.f + expf(-(gp + b_gate[0])));

  float sc[NBLK];
#pragma unroll
  for (int n = 0; n < NBLK; ++n){
    float p = 0.f;
    const float4* kr = (const float4*)(Ks + n*RS + c*QS);
#pragma unroll
    for (int j = 0; j < 8; ++j){
      float4 u = kr[j];
      p += qv[4*j+0]*u.x + qv[4*j+1]*u.y + qv[4*j+2]*u.z + qv[4*j+3]*u.w;
    }
    p += __shfl_xor(p, 1); p += __shfl_xor(p, 2);
    sc[n] = p * SCALE;
  }
  float m = sc[0];
#pragma unroll
  for (int n = 1; n < NBLK; ++n) m = fmaxf(m, sc[n]);
  float l = 0.f;
#pragma unroll
  for (int n = 0; n < NBLK; ++n){ sc[n] = expf(sc[n]-m); l += sc[n]; }
  float inv = 1.f/l;
#pragma unroll
  for (int n = 0; n < NBLK; ++n) sc[n] *= inv;

#pragma unroll
  for (int n = 0; n < NBLK; ++n){
    float t2 = sc[n];
    t2 += __shfl_xor(t2, 4); t2 += __shfl_xor(t2, 8);
    t2 += __shfl_xor(t2, 16); t2 += __shfl_xor(t2, 32);
    if ((tid & 63) == 0) wsum[tid>>6][n] = t2;
  }
  __syncthreads();
  if (tid < NBLK)
    pooled_part[(size_t)blk*NBLK + tid] =
        (wsum[0][tid]+wsum[1][tid]) + (wsum[2][tid]+wsum[3][tid]);

  float o[32];
#pragma unroll
  for (int d = 0; d < 32; ++d) o[d] = 0.f;
#pragma unroll
  for (int n = 0; n < NBLK; ++n){
    float pb = sc[n];
    const float4* vr = (const float4*)(Vs + n*RS + c*QS);
#pragma unroll
    for (int j = 0; j < 8; ++j){
      float4 u = vr[j];
      o[4*j+0] += pb*u.x; o[4*j+1] += pb*u.y;
      o[4*j+2] += pb*u.z; o[4*j+3] += pb*u.w;
    }
  }
  float* op = out + ((size_t)row*QH + g*NH + h)*DIM + c*32;
#pragma unroll
  for (int d = 0; d < 32; ++d) op[d] = g0*o[d];   // overwrite (first branch)
}

// ---- kernel 3: role-split topk+slc | win attention (MFMA, async dbuf) ------
// grid 1024; idx&7 encodes (bb,g) twice -> same-(bb,g) blocks share XCDs.
// Swapped QK^T: C[col=l15=query][row=quad*4+r=key] -> lane-local softmax.
// Layouts (m89/m91/m120): A[m=lane&15][k=quad*8+j], B[k=quad*8+j][n=lane&15],
// C[col=lane&15,row=quad*4+r]
__global__ __launch_bounds__(256, 2) void attn_k(
    const float* __restrict__ q, const ushort_t* __restrict__ Kb,
    const ushort_t* __restrict__ VT, const float* __restrict__ pp,
    const float* __restrict__ w_gate, const float* __restrict__ b_gate,
    float* __restrict__ slcbuf, float* __restrict__ out)
{
  int idx = blockIdx.x;
  int x = idx & 7, low = idx & 1, u = idx >> 3;
  int bbg = x >> 1;                 // (bb,g)
  int j = u*2 + low;                // 0..255
  int role = j >> 7;                // 0 = slc, 1 = win
  int qb = (j >> 2) & 31;
  int h  = j & 3;
  int bb = bbg >> 1, g = bbg & 1;

  int tid = threadIdx.x;
  int lane = tid & 63, w = tid >> 6, quad = lane >> 4, l15 = lane & 15;
  int xr = (l15 & 7) << 4;          // read-side XOR (matches prep_k store)

  __shared__ ushort_t Ks[2][64*128];    // 32.0 KB (double buffer, linear+swz)
  __shared__ ushort_t VTs[2][128*64];   // 32.0 KB
  __shared__ ushort_t Ps[64*VP];        //  9.0 KB
  __shared__ float gbuf[64];
  __shared__ int   idxs[NTOP];

  // ---- top-k (role 0 only; wave 0; lax.top_k tie rule) ----
  if (role == 0 && tid < 64){
    int n = lane;
    float val = -INFINITY;
    if (n < NBLK){
      const float* p0 = pp + ((size_t)((bb*KV+g)*NQB + qb)*NH)*NBLK + n;
      val = (p0[0] + p0[NBLK]) + (p0[2*NBLK] + p0[3*NBLK]);
    }
    for (int t = 0; t < NTOP; ++t){
      float bv = val; int bi = n;
      for (int mm = 1; mm < 32; mm <<= 1){
        float ov = __shfl_xor(bv, mm);
        int   oi = __shfl_xor(bi, mm);
        if (ov > bv || (ov == bv && oi < bi)){ bv = ov; bi = oi; }
      }
      if (lane == 0) idxs[t] = bi;
      if (n == bi) val = -INFINITY;
    }
  }

  // ---- Q fragments direct from global + exact fp32 gate (role-selected) ----
  const float* qrow = q + ((size_t)(bb*SEQ + qb*64 + w*16 + l15)*QH + g*NH + h)*DIM;
  int gcol = 1 + role;
  bf16x8 qfrag[4];
  float gp = 0.f;
#pragma unroll
  for (int kc = 0; kc < 4; ++kc){
    int d0 = kc*32 + quad*8;
    float4 u0 = *(const float4*)(qrow + d0);
    float4 u1 = *(const float4*)(qrow + d0 + 4);
    float qf[8] = {u0.x,u0.y,u0.z,u0.w,u1.x,u1.y,u1.z,u1.w};
#pragma unroll
    for (int jj = 0; jj < 8; ++jj) gp += qf[jj]*w_gate[(d0+jj)*3 + gcol];
    union { unsigned uu[4]; bf16x8 v8; } tq;
    tq.uu[0] = pkbf(u0.x,u0.y); tq.uu[1] = pkbf(u0.z,u0.w);
    tq.uu[2] = pkbf(u1.x,u1.y); tq.uu[3] = pkbf(u1.z,u1.w);
    qfrag[kc] = tq.v8;
  }
  gp += __shfl_xor(gp,16); gp += __shfl_xor(gp,32);
  if (quad == 0) gbuf[w*16+l15] = 1.f/(1.f + __expf(-(gp + b_gate[gcol])));
  __syncthreads();   // publishes gbuf + idxs
  float gl[4];
#pragma unroll
  for (int r = 0; r < 4; ++r) gl[r] = gbuf[w*16+quad*4+r];

  const ushort_t* kbase  = Kb + (size_t)bbg*SEQ*DIM;
  const ushort_t* vtbase = VT + (size_t)bbg*DIM*SEQ;

  int kb0 = (qb >= 8) ? (qb - 8) : 0;
  int nph = (role == 0) ? NTOP : (qb - kb0 + 1);
  int qi_local = w*16 + l15;

  float m1 = -INFINITY, l1 = 0.f;
  f32x4 oacc[8];
  const f32x4 zero4 = {0.f,0.f,0.f,0.f};
#pragma unroll
  for (int dt = 0; dt < 8; ++dt) oacc[dt] = zero4;

  // staging: 8 async 16B direct-to-LDS loads per thread; LDS dest linear
  // (wave-uniform base), global src per-lane & pre-swizzled by prep_k.
  auto stage = [&](int bufi, int kb_){
    const ushort_t* ksrc = kbase + (size_t)kb_*64*DIM;
#pragma unroll
    for (int jj = 0; jj < 4; ++jj){
      int i = tid + jj*256;                     // K tile: 1024 16B units
      async16(&Ks[bufi][(jj*256 + w*64)*8], ksrc + (size_t)i*8);
    }
    const ushort_t* vsrc = vtbase + kb_*64;
#pragma unroll
    for (int jj = 0; jj < 4; ++jj){
      int i = tid + jj*256;                     // VT tile: [d=128][64]
      int d = i >> 3, sg = i & 7;
      async16(&VTs[bufi][(jj*256 + w*64)*8], vsrc + (size_t)d*SEQ + sg*8);
    }
  };

  stage(0, (role == 0) ? idxs[0] : kb0);

  for (int t = 0; t < nph; ++t){
    int cur = t & 1;
    int kb = (role == 0) ? idxs[t] : (kb0 + t);
    // vmcnt(0)+lgkmcnt(0) drain + barrier: buf[cur] resident in LDS for all
    // waves; all waves done reading buf[cur^1] -> safe to overwrite it.
    __syncthreads();
    if (t+1 < nph){
      int kbn = (role == 0) ? idxs[t+1] : (kb0 + t + 1);
      stage(cur ^ 1, kbn);                      // flies under this phase
    }
    __builtin_amdgcn_sched_barrier(0);          // pin prefetch issue early

    // ---- QK^T swapped: mfma(K, Q) ----
    f32x4 sacc[4];
#pragma unroll
    for (int nt = 0; nt < 4; ++nt) sacc[nt] = zero4;
    __builtin_amdgcn_s_setprio(1);
#pragma unroll
    for (int kc = 0; kc < 4; ++kc){
      bf16x8 b = qfrag[kc];
#pragma unroll
      for (int nt = 0; nt < 4; ++nt){
        bf16x8 a = *(bf16x8*)((char*)&Ks[cur][0] + (nt*16 + l15)*256
                              + ((kc*64 + quad*16) ^ xr));
        sacc[nt] = __builtin_amdgcn_mfma_f32_16x16x32_bf16(a, b, sacc[nt], 0, 0, 0);
      }
    }
    __builtin_amdgcn_s_setprio(0);

    // ---- lane-local softmax over 64 keys (16 in-reg + 2 shfl) ----
    bool mlow  = (role == 1) && (kb == qb - 8);   // valid: key >= qi
    bool mhigh = (role == 1) && (kb == qb);       // valid: key <= qi
    float mx = -INFINITY;
    if (mlow | mhigh){
#pragma unroll
      for (int nt = 0; nt < 4; ++nt)
#pragma unroll
        for (int r = 0; r < 4; ++r){
          int key = nt*16 + quad*4 + r;
          float sv = sacc[nt][r]*SCALE;
          bool valid = (!mlow || key >= qi_local) && (!mhigh || key <= qi_local);
          sv = valid ? sv : -INFINITY;
          sacc[nt][r] = sv;
          mx = fmaxf(mx, sv);
        }
    } else {
#pragma unroll
      for (int nt = 0; nt < 4; ++nt)
#pragma unroll
        for (int r = 0; r < 4; ++r){
          float sv = sacc[nt][r]*SCALE;
          sacc[nt][r] = sv;
          mx = fmaxf(mx, sv);
        }
    }
    mx = fmaxf(mx, __shfl_xor(mx, 16));
    mx = fmaxf(mx, __shfl_xor(mx, 32));
    float mn = fmaxf(m1, mx);
    float al = __expf(m1 - mn);
    float s0 = 0.f;
#pragma unroll
    for (int nt = 0; nt < 4; ++nt)
#pragma unroll
      for (int r = 0; r < 4; ++r){
        float pe = __expf(sacc[nt][r] - mn);    // masked -> 0
        sacc[nt][r] = pe;
        s0 += pe;
      }
    s0 += __shfl_xor(s0, 16);
    s0 += __shfl_xor(s0, 32);
    l1 = l1*al + s0;
    m1 = mn;

    // ---- P -> LDS bf16, packed b64 (row = query; wave-private) ----
#pragma unroll
    for (int nt = 0; nt < 4; ++nt){
      uint2 pk;
      pk.x = pkbf(sacc[nt][0], sacc[nt][1]);
      pk.y = pkbf(sacc[nt][2], sacc[nt][3]);
      *(uint2*)&Ps[(w*16 + l15)*VP + nt*16 + quad*4] = pk;
    }

    // ---- rescale + PV ----
    float ar[4];
#pragma unroll
    for (int r = 0; r < 4; ++r) ar[r] = __shfl(al, quad*4 + r);
#pragma unroll
    for (int dt = 0; dt < 8; ++dt)
#pragma unroll
      for (int r = 0; r < 4; ++r) oacc[dt][r] *= ar[r];
#pragma unroll
    for (int kc2 = 0; kc2 < 2; ++kc2){
      bf16x8 pa = *(bf16x8*)&Ps[(w*16 + l15)*VP + kc2*32 + quad*8];
      __builtin_amdgcn_s_setprio(1);
#pragma unroll
      for (int dt = 0; dt < 8; ++dt){
        bf16x8 vb8 = *(bf16x8*)((char*)&VTs[cur][0] + (dt*16 + l15)*128
                                + ((kc2*64 + quad*16) ^ xr));
        oacc[dt] = __builtin_amdgcn_mfma_f32_16x16x32_bf16(pa, vb8, oacc[dt], 0, 0, 0);
      }
      __builtin_amdgcn_s_setprio(0);
    }
  }

  // ---- epilogue: race-free plain stores ----
  float lr[4];
#pragma unroll
  for (int r = 0; r < 4; ++r) lr[r] = __shfl(l1, quad*4 + r);
#pragma unroll
  for (int r = 0; r < 4; ++r){
    float s2 = gl[r] / lr[r];
    size_t ob = ((size_t)(bb*SEQ + qb*64 + w*16 + quad*4 + r)*QH + g*NH + h)*DIM + l15;
    if (role == 0){
      float* op = slcbuf + ob;              // unique writer; full coverage
#pragma unroll
      for (int dt = 0; dt < 8; ++dt) op[dt*16] = s2 * oacc[dt][r];
    } else {
      float* op = out + ob;                 // unique writer; cmp already done
#pragma unroll
      for (int dt = 0; dt < 8; ++dt) op[dt*16] += s2 * oacc[dt][r];
    }
  }
}

// ---------------- kernel 4: merge (out += slcbuf) ---------------------------
__global__ __launch_bounds__(256) void merge_k(const float* __restrict__ slcbuf,
                                               float* __restrict__ out){
  int i = blockIdx.x * 256 + threadIdx.x;   // over 4096*8*128/4 float4s
  float4 a = ((const float4*)slcbuf)[i];
  float4 b = ((float4*)out)[i];
  b.x += a.x; b.y += a.y; b.z += a.z; b.w += a.w;
  ((float4*)out)[i] = b;
}

extern "C" void kernel_launch(void* const* d_in, const int* in_sizes, int n_in,
                              void* d_out, int out_size, void* d_ws, size_t ws_size,
                              hipStream_t stream) {
  const float* q      = (const float*)d_in[0];
  const float* k      = (const float*)d_in[1];
  const float* v      = (const float*)d_in[2];
  const float* w_k    = (const float*)d_in[3];
  const float* b_k    = (const float*)d_in[4];
  const float* w_v    = (const float*)d_in[5];
  const float* b_v    = (const float*)d_in[6];
  const float* w_gate = (const float*)d_in[7];
  const float* b_gate = (const float*)d_in[8];
  float* out = (float*)d_out;

  float* ws     = (float*)d_ws;
  float* Kc     = ws;                        // 16384 f32
  float* Vc     = ws + 16384;                // 16384 f32
  float* pp     = ws + 32768;                // 512*32 f32
  float* slcbuf = ws + 49152;                // 4.19M f32 (16.8 MB)
  ushort_t* Kb  = (ushort_t*)(ws + 4243456); // 4*2048*128 bf16 (2 MB)
  ushort_t* VT  = Kb + 1048576;              // 4*128*2048 bf16 (2 MB)

  prep_k    <<<256, 256, 0, stream>>>(k, v, Kb, VT);
  compress_k<<<256, 256, 0, stream>>>(k, v, w_k, b_k, w_v, b_v, Kc, Vc);
  cmp_attn_k<<<NB*KV*NQB*NH, 256, 0, stream>>>(q, Kc, Vc, w_gate, b_gate, pp, out);
  attn_k    <<<1024, 256, 0, stream>>>(q, Kb, VT, pp, w_gate, b_gate, slcbuf, out);
  merge_k   <<<4096, 256, 0, stream>>>(slcbuf, out);
}

// Round 2
// 186.005 us; speedup vs baseline: 1.0709x; 1.0023x over previous
//
#include <hip/hip_runtime.h>
#include <hip/hip_bf16.h>

// NSA forward, MI355X round 12. All inputs fp32, output fp32.
// r11 + h-merged attn_k: block = (bbg, qb, role), 512 threads / 8 waves;
// wave w -> head (w&3), query-half (w>>2). One K/V staging feeds all 4 heads
// (4x MFMA:staging amortization, 4x fewer barriers/top-k). Q pre-scaled by
// SCALE*log2e -> exp2f softmax; defer-max (thr=8, log2 domain) skips O-rescale.
// LDS 101 KB -> 1 block/CU (8 waves). Grid 256, XCD-aware mapping.
// Shapes: S=4096, seqlen=2048, qh=8, kvh=2, dim=128, blk=64, TOPK=16,
// window=(512,0).

#define SEQ   2048
#define NB    2
#define KV    2
#define NH    4
#define QH    8
#define DIM   128
#define NBLK  32
#define NQB   32
#define NTOP  16
#define SCALE 0.08838834764831845f   // 128^-0.5
#define QSC   0.12751831795244785f   // SCALE * log2(e)
#define QS    36                     // cmp LDS quarter stride (floats)
#define RS    144                    // cmp LDS row stride
#define VP    72                     // P/prep-T LDS row stride (bf16): pad 8

typedef unsigned short ushort_t;
using bf16x8 = __attribute__((ext_vector_type(8))) short;
using f32x4  = __attribute__((ext_vector_type(4))) float;

__device__ __forceinline__ unsigned pkbf(float a, float b){
  union { __hip_bfloat162 h; unsigned u; } cv;
  cv.h = __float22bfloat162_rn(make_float2(a, b));
  return cv.u;
}

// async 16B direct-to-LDS copy (per-lane global src, wave-uniform LDS base)
__device__ __forceinline__ void async16(ushort_t* l, const ushort_t* g){
  __builtin_amdgcn_global_load_lds(
      (const __attribute__((address_space(1))) unsigned int*)(size_t)g,
      (__attribute__((address_space(3))) unsigned int*)(size_t)l,
      16, 0, 0);
}

// ---------------- kernel 0: K/V bf16 preprocessing --------------------------
// Kb row-major [bbg][row][128] bf16, each 256B row stored XOR-swizzled:
// byte ^= (row&7)<<4.  VT transposed [bbg][d][SEQ] bf16; within each 128B
// (64-seq) tile: byte ^= (d&7)<<4.  attn_k's global_load_lds then lands a
// swizzled LDS tile from a LINEAR copy; ds_reads apply the same XOR.
__global__ __launch_bounds__(256) void prep_k(
    const float* __restrict__ k, const float* __restrict__ v,
    ushort_t* __restrict__ Kb, ushort_t* __restrict__ VT)
{
  int blk = blockIdx.x;
  int db = blk & 1, rb = (blk >> 1) & 31, bbg = blk >> 6;
  int bb = bbg >> 1, g = bbg & 1;
  int tid = threadIdx.x;
  __shared__ ushort_t T[64*VP];    // [d 0..63][key 0..63], pad 8

  for (int jj = 0; jj < 4; ++jj){
    int i = tid + jj*256;                 // 1024 float4 units (64 rows x 16)
    int r = i >> 4, ds = i & 15;
    size_t src = ((size_t)(bb*SEQ + rb*64 + r)*KV + g)*DIM + db*64 + ds*4;
    float4 kx = *(const float4*)(k + src);
    float4 vx = *(const float4*)(v + src);
    uint2 kk; kk.x = pkbf(kx.x,kx.y); kk.y = pkbf(kx.z,kx.w);
    size_t rowb = ((size_t)bbg*SEQ + rb*64 + r)*DIM*2;        // row base bytes
    int swz = (db*128 + ds*8) ^ ((r & 7) << 4);               // within-row
    *(uint2*)((char*)Kb + rowb + swz) = kk;
    unsigned v01 = pkbf(vx.x,vx.y), v23 = pkbf(vx.z,vx.w);
    T[(ds*4+0)*VP + r] = (ushort_t)(v01 & 0xffffu);
    T[(ds*4+1)*VP + r] = (ushort_t)(v01 >> 16);
    T[(ds*4+2)*VP + r] = (ushort_t)(v23 & 0xffffu);
    T[(ds*4+3)*VP + r] = (ushort_t)(v23 >> 16);
  }
  __syncthreads();
  for (int jj = 0; jj < 4; ++jj){
    int i = tid + jj*256;                 // 1024 8B units (64 d x 16)
    int d = i >> 4, seg = i & 15;
    uint2 u = *(uint2*)&T[d*VP + seg*4];
    size_t rowb = ((size_t)bbg*DIM + db*64 + d)*SEQ*2;        // d-row bytes
    int swz = (seg*8) ^ ((d & 7) << 4);                       // within 128B tile
    *(uint2*)((char*)VT + rowb + rb*128 + swz) = u;
  }
}

// ---------------- kernel 1: block compression (fp32 out to ws) --------------
__global__ __launch_bounds__(256) void compress_k(
    const float* __restrict__ k, const float* __restrict__ v,
    const float* __restrict__ w_k, const float* __restrict__ b_k,
    const float* __restrict__ w_v, const float* __restrict__ b_v,
    float* __restrict__ Kc, float* __restrict__ Vc)
{
  int blk = blockIdx.x;            // (bb,g,n,dhalf)
  int dh = blk & 1;
  int n  = (blk >> 1) & 31;
  int g  = (blk >> 6) & 1;
  int bb = blk >> 7;
  int tid = threadIdx.x;

  __shared__ float wks[64], wvs[64];
  __shared__ float accK[16][64], accV[16][64];
  if (tid < 64){ wks[tid] = w_k[tid]; wvs[tid] = w_v[tid]; }
  __syncthreads();

  int r4 = tid >> 4, dq = tid & 15;
  float4 sk = {0,0,0,0}, sv = {0,0,0,0};
  for (int rr = 0; rr < 4; ++rr){
    int row = r4*4 + rr;
    size_t off = ((size_t)(bb*SEQ + n*64 + row)*KV + g)*DIM + dh*64 + dq*4;
    float4 kx = *(const float4*)(k + off);
    float4 vx = *(const float4*)(v + off);
    float a = wks[row], b = wvs[row];
    sk.x += a*kx.x; sk.y += a*kx.y; sk.z += a*kx.z; sk.w += a*kx.w;
    sv.x += b*vx.x; sv.y += b*vx.y; sv.z += b*vx.z; sv.w += b*vx.w;
  }
  *(float4*)&accK[r4][dq*4] = sk;
  *(float4*)&accV[r4][dq*4] = sv;
  __syncthreads();
  size_t obase = ((size_t)((bb*KV+g)*NBLK + n))*DIM + dh*64;
  if (tid < 64){
    float s = 0.f;
#pragma unroll
    for (int i = 0; i < 16; ++i) s += accK[i][tid];
    Kc[obase + tid] = s + b_k[0];
  } else if (tid < 128){
    int d = tid - 64;
    float s = 0.f;
#pragma unroll
    for (int i = 0; i < 16; ++i) s += accV[i][d];
    Vc[obase + d] = s + b_v[0];
  }
}

// ------- kernel 2: compressed attention (fp32 VALU; exact pooled P) ---------
__global__ __launch_bounds__(256) void cmp_attn_k(
    const float* __restrict__ q, const float* __restrict__ Kc,
    const float* __restrict__ Vc,
    const float* __restrict__ w_gate, const float* __restrict__ b_gate,
    float* __restrict__ pooled_part, float* __restrict__ out)
{
  int blk = blockIdx.x;
  int h  = blk & 3;
  int qb = (blk >> 2) & (NQB-1);
  int g  = (blk >> 7) & 1;
  int bb = blk >> 8;
  int tid = threadIdx.x;
  int qi = tid >> 2, c = tid & 3;

  __shared__ float Ks[32*RS];
  __shared__ float Vs[32*RS];
  __shared__ float wsum[4][NBLK];

  const float4* Ksrc = (const float4*)(Kc + (size_t)(bb*KV + g) * NBLK * DIM);
  const float4* Vsrc = (const float4*)(Vc + (size_t)(bb*KV + g) * NBLK * DIM);
  for (int i = tid; i < 1024; i += 256){
    int row = i >> 5, seg = i & 31;
    int dst = row*RS + (seg>>3)*QS + (seg&7)*4;
    ((float4*)(Ks+dst))[0] = Ksrc[i];
    ((float4*)(Vs+dst))[0] = Vsrc[i];
  }
  __syncthreads();

  int row = bb*SEQ + qb*64 + qi;
  float qv[32];
  {
    const float4* q4 = (const float4*)(q + ((size_t)row*QH + g*NH + h)*DIM + c*32);
#pragma unroll
    for (int j = 0; j < 8; ++j){
      float4 u = q4[j];
      qv[4*j+0]=u.x; qv[4*j+1]=u.y; qv[4*j+2]=u.z; qv[4*j+3]=u.w;
    }
  }

  float gp = 0.f;
#pragma unroll
  for (int d = 0; d < 32; ++d) gp += qv[d]*w_gate[(c*32+d)*3 + 0];
  gp += __shfl_xor(gp, 1); gp += __shfl_xor(gp, 2);
  float g0 = 1.f/(1.f + expf(-(gp + b_gate[0])));

  float sc[NBLK];
#pragma unroll
  for (int n = 0; n < NBLK; ++n){
    float p = 0.f;
    const float4* kr = (const float4*)(Ks + n*RS + c*QS);
#pragma unroll
    for (int j = 0; j < 8; ++j){
      float4 u = kr[j];
      p += qv[4*j+0]*u.x + qv[4*j+1]*u.y + qv[4*j+2]*u.z + qv[4*j+3]*u.w;
    }
    p += __shfl_xor(p, 1); p += __shfl_xor(p, 2);
    sc[n] = p * SCALE;
  }
  float m = sc[0];
#pragma unroll
  for (int n = 1; n < NBLK; ++n) m = fmaxf(m, sc[n]);
  float l = 0.f;
#pragma unroll
  for (int n = 0; n < NBLK; ++n){ sc[n] = expf(sc[n]-m); l += sc[n]; }
  float inv = 1.f/l;
#pragma unroll
  for (int n = 0; n < NBLK; ++n) sc[n] *= inv;

#pragma unroll
  for (int n = 0; n < NBLK; ++n){
    float t2 = sc[n];
    t2 += __shfl_xor(t2, 4); t2 += __shfl_xor(t2, 8);
    t2 += __shfl_xor(t2, 16); t2 += __shfl_xor(t2, 32);
    if ((tid & 63) == 0) wsum[tid>>6][n] = t2;
  }
  __syncthreads();
  if (tid < NBLK)
    pooled_part[(size_t)blk*NBLK + tid] =
        (wsum[0][tid]+wsum[1][tid]) + (wsum[2][tid]+wsum[3][tid]);

  float o[32];
#pragma unroll
  for (int d = 0; d < 32; ++d) o[d] = 0.f;
#pragma unroll
  for (int n = 0; n < NBLK; ++n){
    float pb = sc[n];
    const float4* vr = (const float4*)(Vs + n*RS + c*QS);
#pragma unroll
    for (int j = 0; j < 8; ++j){
      float4 u = vr[j];
      o[4*j+0] += pb*u.x; o[4*j+1] += pb*u.y;
      o[4*j+2] += pb*u.z; o[4*j+3] += pb*u.w;
    }
  }
  float* op = out + ((size_t)row*QH + g*NH + h)*DIM + c*32;
#pragma unroll
  for (int d = 0; d < 32; ++d) op[d] = g0*o[d];   // overwrite (first branch)
}

// ---- kernel 3: h-merged role-split topk+slc | win attention (MFMA) ---------
// grid 256, 512 threads. block = (bbg, qb, role); wave w: head w&3, qhalf w>>2.
// One K/V stage per phase feeds 8 waves x 64 MFMA. Swapped QK^T:
// C[col=l15=query][row=quad*4+r=key] -> lane-local softmax.
// Layouts (m89/m91/m120): A[m=lane&15][k=quad*8+j], B[k=quad*8+j][n=lane&15],
// C[col=lane&15,row=quad*4+r]
__global__ __launch_bounds__(512, 2) void attn_k(
    const float* __restrict__ q, const ushort_t* __restrict__ Kb,
    const ushort_t* __restrict__ VT, const float* __restrict__ pp,
    const float* __restrict__ w_gate, const float* __restrict__ b_gate,
    float* __restrict__ slcbuf, float* __restrict__ out)
{
  int idx = blockIdx.x;             // 256 blocks
  int x = idx & 7, low = idx & 1, u = idx >> 3;
  int bbg = x >> 1;                 // (bb,g): same-bbg blocks share XCD pair
  int j = u*2 + low;                // 0..63
  int role = j >> 5;                // 0 = slc, 1 = win
  int qb = j & 31;
  int bb = bbg >> 1, g = bbg & 1;

  int tid = threadIdx.x;
  int lane = tid & 63, w = tid >> 6;        // wave 0..7
  int quad = lane >> 4, l15 = lane & 15;
  int h = w & 3, qh2 = w >> 2;              // head, query half
  int xr = (l15 & 7) << 4;                  // read-side XOR (matches prep_k)

  __shared__ ushort_t Ks[2][64*128];    // 32.0 KB (double buffer, linear+swz)
  __shared__ ushort_t VTs[2][128*64];   // 32.0 KB
  __shared__ ushort_t Ps[256*VP];       // 36.0 KB (per-wave 32-row slabs)
  __shared__ float gbuf[256];
  __shared__ int   idxs[NTOP];

  // ---- top-k (role 0 only; wave 0; lax.top_k tie rule) ----
  if (role == 0 && tid < 64){
    int n = lane;
    float val = -INFINITY;
    if (n < NBLK){
      const float* p0 = pp + ((size_t)((bb*KV+g)*NQB + qb)*NH)*NBLK + n;
      val = (p0[0] + p0[NBLK]) + (p0[2*NBLK] + p0[3*NBLK]);
    }
    for (int t = 0; t < NTOP; ++t){
      float bv = val; int bi = n;
      for (int mm = 1; mm < 32; mm <<= 1){
        float ov = __shfl_xor(bv, mm);
        int   oi = __shfl_xor(bi, mm);
        if (ov > bv || (ov == bv && oi < bi)){ bv = ov; bi = oi; }
      }
      if (lane == 0) idxs[t] = bi;
      if (n == bi) val = -INFINITY;
    }
  }

  // ---- Q fragments (pre-scaled by SCALE*log2e) + exact fp32 gate ----
  const float* qrow0 = q + ((size_t)(bb*SEQ + qb*64 + qh2*32 + l15)*QH + g*NH + h)*DIM;
  const float* qrow1 = qrow0 + (size_t)16*QH*DIM;
  int gcol = 1 + role;
  bf16x8 qfrag0[4], qfrag1[4];
  float gp0 = 0.f, gp1 = 0.f;
#pragma unroll
  for (int kc = 0; kc < 4; ++kc){
    int d0 = kc*32 + quad*8;
    float4 a0 = *(const float4*)(qrow0 + d0);
    float4 a1 = *(const float4*)(qrow0 + d0 + 4);
    float4 b0 = *(const float4*)(qrow1 + d0);
    float4 b1 = *(const float4*)(qrow1 + d0 + 4);
    float qa[8] = {a0.x,a0.y,a0.z,a0.w,a1.x,a1.y,a1.z,a1.w};
    float qc[8] = {b0.x,b0.y,b0.z,b0.w,b1.x,b1.y,b1.z,b1.w};
#pragma unroll
    for (int jj = 0; jj < 8; ++jj){
      float wg = w_gate[(d0+jj)*3 + gcol];
      gp0 += qa[jj]*wg; gp1 += qc[jj]*wg;
    }
    union { unsigned uu[4]; bf16x8 v8; } t0, t1;
#pragma unroll
    for (int p2 = 0; p2 < 4; ++p2){
      t0.uu[p2] = pkbf(qa[2*p2]*QSC, qa[2*p2+1]*QSC);
      t1.uu[p2] = pkbf(qc[2*p2]*QSC, qc[2*p2+1]*QSC);
    }
    qfrag0[kc] = t0.v8; qfrag1[kc] = t1.v8;
  }
  gp0 += __shfl_xor(gp0,16); gp0 += __shfl_xor(gp0,32);
  gp1 += __shfl_xor(gp1,16); gp1 += __shfl_xor(gp1,32);
  if (quad == 0){
    gbuf[w*32 + l15]      = 1.f/(1.f + __expf(-(gp0 + b_gate[gcol])));
    gbuf[w*32 + 16 + l15] = 1.f/(1.f + __expf(-(gp1 + b_gate[gcol])));
  }
  __syncthreads();   // publishes gbuf + idxs
  float gl0[4], gl1[4];
#pragma unroll
  for (int r = 0; r < 4; ++r){
    gl0[r] = gbuf[w*32 + quad*4 + r];
    gl1[r] = gbuf[w*32 + 16 + quad*4 + r];
  }

  const ushort_t* kbase  = Kb + (size_t)bbg*SEQ*DIM;
  const ushort_t* vtbase = VT + (size_t)bbg*DIM*SEQ;

  int kb0 = (qb >= 8) ? (qb - 8) : 0;
  int nph = (role == 0) ? NTOP : (qb - kb0 + 1);
  int qi0 = qh2*32 + l15, qi1 = qi0 + 16;   // lane-local query indices

  float m10 = -INFINITY, l10 = 0.f, m11 = -INFINITY, l11 = 0.f;
  f32x4 oacc0[8], oacc1[8];
  const f32x4 zero4 = {0.f,0.f,0.f,0.f};
#pragma unroll
  for (int dt = 0; dt < 8; ++dt){ oacc0[dt] = zero4; oacc1[dt] = zero4; }

  // staging: 512 threads x 2 units x 16B per tile; LDS dest linear
  // (wave-uniform base), global src per-lane & pre-swizzled by prep_k.
  auto stage = [&](int bufi, int kb_){
    const ushort_t* ksrc = kbase + (size_t)kb_*64*DIM;
#pragma unroll
    for (int jj = 0; jj < 2; ++jj)          // K tile: 1024 16B units
      async16(&Ks[bufi][(jj*512 + w*64)*8], ksrc + (size_t)(tid + jj*512)*8);
    const ushort_t* vsrc = vtbase + kb_*64;
#pragma unroll
    for (int jj = 0; jj < 2; ++jj){         // VT tile: [d=128][64]
      int i = tid + jj*512;
      int d = i >> 3, sg = i & 7;
      async16(&VTs[bufi][(jj*512 + w*64)*8], vsrc + (size_t)d*SEQ + sg*8);
    }
  };

  stage(0, (role == 0) ? idxs[0] : kb0);

  for (int t = 0; t < nph; ++t){
    int cur = t & 1;
    int kb = (role == 0) ? idxs[t] : (kb0 + t);
    // vmcnt(0)+lgkmcnt(0) drain + barrier: buf[cur] resident; buf[cur^1] free.
    __syncthreads();
    if (t+1 < nph){
      int kbn = (role == 0) ? idxs[t+1] : (kb0 + t + 1);
      stage(cur ^ 1, kbn);                  // flies under this phase
    }
    __builtin_amdgcn_sched_barrier(0);      // pin prefetch issue early

    // ---- QK^T swapped: mfma(K, Q); K A-frags shared across both q-tiles ----
    f32x4 sacc0[4], sacc1[4];
#pragma unroll
    for (int nt = 0; nt < 4; ++nt){ sacc0[nt] = zero4; sacc1[nt] = zero4; }
    __builtin_amdgcn_s_setprio(1);
#pragma unroll
    for (int kc = 0; kc < 4; ++kc){
#pragma unroll
      for (int nt = 0; nt < 4; ++nt){
        bf16x8 a = *(bf16x8*)((char*)&Ks[cur][0] + (nt*16 + l15)*256
                              + ((kc*64 + quad*16) ^ xr));
        sacc0[nt] = __builtin_amdgcn_mfma_f32_16x16x32_bf16(a, qfrag0[kc], sacc0[nt], 0, 0, 0);
        sacc1[nt] = __builtin_amdgcn_mfma_f32_16x16x32_bf16(a, qfrag1[kc], sacc1[nt], 0, 0, 0);
      }
    }
    __builtin_amdgcn_s_setprio(0);

    bool mlow  = (role == 1) && (kb == qb - 8);   // valid: key >= qi
    bool mhigh = (role == 1) && (kb == qb);       // valid: key <= qi
    bool domask = mlow | mhigh;

    // ---- lane-local softmax per q-tile (scores already in log2 domain) ----
    auto softmax_qt = [&](f32x4* sc, float& m1r, float& l1r, int qi_l,
                          bool& skipped) -> float {
      float mx = -INFINITY;
      if (domask){
#pragma unroll
        for (int nt = 0; nt < 4; ++nt)
#pragma unroll
          for (int r = 0; r < 4; ++r){
            int key = nt*16 + quad*4 + r;
            float sv = sc[nt][r];
            bool valid = (!mlow || key >= qi_l) && (!mhigh || key <= qi_l);
            sv = valid ? sv : -INFINITY;
            sc[nt][r] = sv;
            mx = fmaxf(mx, sv);
          }
      } else {
#pragma unroll
        for (int nt = 0; nt < 4; ++nt)
#pragma unroll
          for (int r = 0; r < 4; ++r) mx = fmaxf(mx, sc[nt][r]);
      }
      mx = fmaxf(mx, __shfl_xor(mx, 16));
      mx = fmaxf(mx, __shfl_xor(mx, 32));
      float al = 1.f;
      skipped = __all(mx <= m1r + 8.f);     // defer-max: P bounded by 2^8
      if (!skipped){
        float mn = fmaxf(m1r, mx);
        al = exp2f(m1r - mn);
        m1r = mn;
      }
      float s0 = 0.f;
#pragma unroll
      for (int nt = 0; nt < 4; ++nt)
#pragma unroll
        for (int r = 0; r < 4; ++r){
          float pe = exp2f(sc[nt][r] - m1r);   // masked -> 0
          sc[nt][r] = pe;
          s0 += pe;
        }
      s0 += __shfl_xor(s0, 16);
      s0 += __shfl_xor(s0, 32);
      l1r = l1r*al + s0;
      return al;
    };
    bool sk0, sk1;
    float al0 = softmax_qt(sacc0, m10, l10, qi0, sk0);
    float al1 = softmax_qt(sacc1, m11, l11, qi1, sk1);

    // ---- P -> LDS bf16, packed b64 (row = query; wave-private slab) ----
#pragma unroll
    for (int nt = 0; nt < 4; ++nt){
      uint2 p0, p1;
      p0.x = pkbf(sacc0[nt][0], sacc0[nt][1]);
      p0.y = pkbf(sacc0[nt][2], sacc0[nt][3]);
      p1.x = pkbf(sacc1[nt][0], sacc1[nt][1]);
      p1.y = pkbf(sacc1[nt][2], sacc1[nt][3]);
      *(uint2*)&Ps[(w*32 + l15)*VP + nt*16 + quad*4] = p0;
      *(uint2*)&Ps[(w*32 + 16 + l15)*VP + nt*16 + quad*4] = p1;
    }

    // ---- O rescale (skipped when defer-max held) ----
    if (!sk0){
      float ar[4];
#pragma unroll
      for (int r = 0; r < 4; ++r) ar[r] = __shfl(al0, quad*4 + r);
#pragma unroll
      for (int dt = 0; dt < 8; ++dt)
#pragma unroll
        for (int r = 0; r < 4; ++r) oacc0[dt][r] *= ar[r];
    }
    if (!sk1){
      float ar[4];
#pragma unroll
      for (int r = 0; r < 4; ++r) ar[r] = __shfl(al1, quad*4 + r);
#pragma unroll
      for (int dt = 0; dt < 8; ++dt)
#pragma unroll
        for (int r = 0; r < 4; ++r) oacc1[dt][r] *= ar[r];
    }

    // ---- PV: V B-frags shared across both q-tiles ----
#pragma unroll
    for (int kc2 = 0; kc2 < 2; ++kc2){
      bf16x8 pa0 = *(bf16x8*)&Ps[(w*32 + l15)*VP + kc2*32 + quad*8];
      bf16x8 pa1 = *(bf16x8*)&Ps[(w*32 + 16 + l15)*VP + kc2*32 + quad*8];
      __builtin_amdgcn_s_setprio(1);
#pragma unroll
      for (int dt = 0; dt < 8; ++dt){
        bf16x8 vb8 = *(bf16x8*)((char*)&VTs[cur][0] + (dt*16 + l15)*128
                                + ((kc2*64 + quad*16) ^ xr));
        oacc0[dt] = __builtin_amdgcn_mfma_f32_16x16x32_bf16(pa0, vb8, oacc0[dt], 0, 0, 0);
        oacc1[dt] = __builtin_amdgcn_mfma_f32_16x16x32_bf16(pa1, vb8, oacc1[dt], 0, 0, 0);
      }
      __builtin_amdgcn_s_setprio(0);
    }
  }

  // ---- epilogue: race-free plain stores ----
  float lr0[4], lr1[4];
#pragma unroll
  for (int r = 0; r < 4; ++r){
    lr0[r] = __shfl(l10, quad*4 + r);
    lr1[r] = __shfl(l11, quad*4 + r);
  }
#pragma unroll
  for (int r = 0; r < 4; ++r){
    float s20 = gl0[r] / lr0[r];
    float s21 = gl1[r] / lr1[r];
    size_t ob0 = ((size_t)(bb*SEQ + qb*64 + qh2*32 + quad*4 + r)*QH + g*NH + h)*DIM + l15;
    size_t ob1 = ob0 + (size_t)16*QH*DIM;
    if (role == 0){
      float* op0 = slcbuf + ob0;            // unique writer; full coverage
      float* op1 = slcbuf + ob1;
#pragma unroll
      for (int dt = 0; dt < 8; ++dt){
        op0[dt*16] = s20 * oacc0[dt][r];
        op1[dt*16] = s21 * oacc1[dt][r];
      }
    } else {
      float* op0 = out + ob0;               // unique writer; cmp already done
      float* op1 = out + ob1;
#pragma unroll
      for (int dt = 0; dt < 8; ++dt){
        op0[dt*16] += s20 * oacc0[dt][r];
        op1[dt*16] += s21 * oacc1[dt][r];
      }
    }
  }
}

// ---------------- kernel 4: merge (out += slcbuf) ---------------------------
__global__ __launch_bounds__(256) void merge_k(const float* __restrict__ slcbuf,
                                               float* __restrict__ out){
  int i = blockIdx.x * 256 + threadIdx.x;   // over 4096*8*128/4 float4s
  float4 a = ((const float4*)slcbuf)[i];
  float4 b = ((float4*)out)[i];
  b.x += a.x; b.y += a.y; b.z += a.z; b.w += a.w;
  ((float4*)out)[i] = b;
}

extern "C" void kernel_launch(void* const* d_in, const int* in_sizes, int n_in,
                              void* d_out, int out_size, void* d_ws, size_t ws_size,
                              hipStream_t stream) {
  const float* q      = (const float*)d_in[0];
  const float* k      = (const float*)d_in[1];
  const float* v      = (const float*)d_in[2];
  const float* w_k    = (const float*)d_in[3];
  const float* b_k    = (const float*)d_in[4];
  const float* w_v    = (const float*)d_in[5];
  const float* b_v    = (const float*)d_in[6];
  const float* w_gate = (const float*)d_in[7];
  const float* b_gate = (const float*)d_in[8];
  float* out = (float*)d_out;

  float* ws     = (float*)d_ws;
  float* Kc     = ws;                        // 16384 f32
  float* Vc     = ws + 16384;                // 16384 f32
  float* pp     = ws + 32768;                // 512*32 f32
  float* slcbuf = ws + 49152;                // 4.19M f32 (16.8 MB)
  ushort_t* Kb  = (ushort_t*)(ws + 4243456); // 4*2048*128 bf16 (2 MB)
  ushort_t* VT  = Kb + 1048576;              // 4*128*2048 bf16 (2 MB)

  prep_k    <<<256, 256, 0, stream>>>(k, v, Kb, VT);
  compress_k<<<256, 256, 0, stream>>>(k, v, w_k, b_k, w_v, b_v, Kc, Vc);
  cmp_attn_k<<<NB*KV*NQB*NH, 256, 0, stream>>>(q, Kc, Vc, w_gate, b_gate, pp, out);
  attn_k    <<<256, 512, 0, stream>>>(q, Kb, VT, pp, w_gate, b_gate, slcbuf, out);
  merge_k   <<<4096, 256, 0, stream>>>(slcbuf, out);
}

// Round 3
// 178.555 us; speedup vs baseline: 1.1156x; 1.0417x over previous
//
#include <hip/hip_runtime.h>
#include <hip/hip_bf16.h>

// NSA forward, MI355X round 13. All inputs fp32, output fp32.
// r12 + (1) cmp_attn_k rewrite: full-dim scores per thread (no per-score
// shfl; was ~194 cross-lane DS ops/thread in dependent chains -> ~6),
// P via padded LDS, pooled via LDS column-sum, lane-local gate.
// (2) compress_k folded into prep_k (same loads). attn_k/merge_k unchanged.
// Shapes: S=4096, seqlen=2048, qh=8, kvh=2, dim=128, blk=64, TOPK=16,
// window=(512,0).

#define SEQ   2048
#define NB    2
#define KV    2
#define NH    4
#define QH    8
#define DIM   128
#define NBLK  32
#define NQB   32
#define NTOP  16
#define SCALE 0.08838834764831845f   // 128^-0.5
#define QSC   0.12751831795244785f   // SCALE * log2(e)
#define QS    36                     // cmp LDS quarter stride (floats)
#define RS    144                    // cmp LDS row stride
#define PLS   33                     // cmp P LDS row stride (floats)
#define VP    72                     // P/prep-T LDS row stride (bf16): pad 8

typedef unsigned short ushort_t;
using bf16x8 = __attribute__((ext_vector_type(8))) short;
using f32x4  = __attribute__((ext_vector_type(4))) float;

__device__ __forceinline__ unsigned pkbf(float a, float b){
  union { __hip_bfloat162 h; unsigned u; } cv;
  cv.h = __float22bfloat162_rn(make_float2(a, b));
  return cv.u;
}

// async 16B direct-to-LDS copy (per-lane global src, wave-uniform LDS base)
__device__ __forceinline__ void async16(ushort_t* l, const ushort_t* g){
  __builtin_amdgcn_global_load_lds(
      (const __attribute__((address_space(1))) unsigned int*)(size_t)g,
      (__attribute__((address_space(3))) unsigned int*)(size_t)l,
      16, 0, 0);
}

// -------- kernel 0: K/V bf16 preprocessing + block compression (fused) ------
// Kb row-major [bbg][row][128] bf16, each 256B row stored XOR-swizzled:
// byte ^= (row&7)<<4.  VT transposed [bbg][d][SEQ] bf16; within each 128B
// (64-seq) tile: byte ^= (d&7)<<4.  Also computes Kc/Vc (w_k/w_v-weighted
// row sums per 64-block) from the same float4 loads.
__global__ __launch_bounds__(256) void prep_k(
    const float* __restrict__ k, const float* __restrict__ v,
    const float* __restrict__ w_k, const float* __restrict__ b_k,
    const float* __restrict__ w_v, const float* __restrict__ b_v,
    ushort_t* __restrict__ Kb, ushort_t* __restrict__ VT,
    float* __restrict__ Kc, float* __restrict__ Vc)
{
  int blk = blockIdx.x;
  int db = blk & 1, rb = (blk >> 1) & 31, bbg = blk >> 6;
  int bb = bbg >> 1, g = bbg & 1;
  int tid = threadIdx.x;
  __shared__ ushort_t T[64*VP];    // [d 0..63][key 0..63], pad 8
  __shared__ float wks[64], wvs[64];
  __shared__ float accK[16][64], accV[16][64];

  if (tid < 64){ wks[tid] = w_k[tid]; wvs[tid] = w_v[tid]; }
  __syncthreads();

  float4 sk = {0,0,0,0}, sv = {0,0,0,0};
  for (int jj = 0; jj < 4; ++jj){
    int i = tid + jj*256;                 // 1024 float4 units (64 rows x 16)
    int r = i >> 4, ds = i & 15;
    size_t src = ((size_t)(bb*SEQ + rb*64 + r)*KV + g)*DIM + db*64 + ds*4;
    float4 kx = *(const float4*)(k + src);
    float4 vx = *(const float4*)(v + src);
    uint2 kk; kk.x = pkbf(kx.x,kx.y); kk.y = pkbf(kx.z,kx.w);
    size_t rowb = ((size_t)bbg*SEQ + rb*64 + r)*DIM*2;        // row base bytes
    int swz = (db*128 + ds*8) ^ ((r & 7) << 4);               // within-row
    *(uint2*)((char*)Kb + rowb + swz) = kk;
    unsigned v01 = pkbf(vx.x,vx.y), v23 = pkbf(vx.z,vx.w);
    T[(ds*4+0)*VP + r] = (ushort_t)(v01 & 0xffffu);
    T[(ds*4+1)*VP + r] = (ushort_t)(v01 >> 16);
    T[(ds*4+2)*VP + r] = (ushort_t)(v23 & 0xffffu);
    T[(ds*4+3)*VP + r] = (ushort_t)(v23 >> 16);
    float a = wks[r], b = wvs[r];
    sk.x += a*kx.x; sk.y += a*kx.y; sk.z += a*kx.z; sk.w += a*kx.w;
    sv.x += b*vx.x; sv.y += b*vx.y; sv.z += b*vx.z; sv.w += b*vx.w;
  }
  *(float4*)&accK[tid>>4][(tid&15)*4] = sk;
  *(float4*)&accV[tid>>4][(tid&15)*4] = sv;
  __syncthreads();

  for (int jj = 0; jj < 4; ++jj){
    int i = tid + jj*256;                 // 1024 8B units (64 d x 16)
    int d = i >> 4, seg = i & 15;
    uint2 u = *(uint2*)&T[d*VP + seg*4];
    size_t rowb = ((size_t)bbg*DIM + db*64 + d)*SEQ*2;        // d-row bytes
    int swz = (seg*8) ^ ((d & 7) << 4);                       // within 128B tile
    *(uint2*)((char*)VT + rowb + rb*128 + swz) = u;
  }

  size_t obase = ((size_t)(bbg*NBLK + rb))*DIM + db*64;
  if (tid < 64){
    float s = 0.f;
#pragma unroll
    for (int i = 0; i < 16; ++i) s += accK[i][tid];
    Kc[obase + tid] = s + b_k[0];
  } else if (tid < 128){
    int d = tid - 64;
    float s = 0.f;
#pragma unroll
    for (int i = 0; i < 16; ++i) s += accV[i][d];
    Vc[obase + d] = s + b_v[0];
  }
}

// ------- kernel 1: compressed attention (fp32 VALU; exact pooled P) ---------
// thread (qi = tid>>2, c = tid&3). Scores: c owns key-blocks n = nn*4+c,
// FULL-dim dots (no shfl). Softmax: 4 shfl total (max/sum over c lanes).
// P -> Pl[64][33] LDS; pooled = 32-thread LDS column sum; PV: c owns
// dim-quarter, P broadcast from LDS. Gate: fully lane-local (full-dim dot).
__global__ __launch_bounds__(256) void cmp_attn_k(
    const float* __restrict__ q, const float* __restrict__ Kc,
    const float* __restrict__ Vc,
    const float* __restrict__ w_gate, const float* __restrict__ b_gate,
    float* __restrict__ pooled_part, float* __restrict__ out)
{
  int blk = blockIdx.x;
  int h  = blk & 3;
  int qb = (blk >> 2) & (NQB-1);
  int g  = (blk >> 7) & 1;
  int bb = blk >> 8;
  int tid = threadIdx.x;
  int qi = tid >> 2, c = tid & 3;

  __shared__ float Ks[32*RS];
  __shared__ float Vs[32*RS];
  __shared__ float Pl[64*PLS];

  const float4* Ksrc = (const float4*)(Kc + (size_t)(bb*KV + g) * NBLK * DIM);
  const float4* Vsrc = (const float4*)(Vc + (size_t)(bb*KV + g) * NBLK * DIM);
  for (int i = tid; i < 1024; i += 256){
    int row = i >> 5, seg = i & 31;
    int dst = row*RS + (seg>>3)*QS + (seg&7)*4;
    ((float4*)(Ks+dst))[0] = Ksrc[i];
    ((float4*)(Vs+dst))[0] = Vsrc[i];
  }
  __syncthreads();

  int row = bb*SEQ + qb*64 + qi;
  const float* qptr = q + ((size_t)row*QH + g*NH + h)*DIM;

  // ---- scores (full-dim, c owns n = nn*4+c) + lane-local gate ----
  float sc[8];
#pragma unroll
  for (int nn = 0; nn < 8; ++nn) sc[nn] = 0.f;
  float gp = 0.f;
  for (int qq = 0; qq < 4; ++qq){
    float qv[32];
    const float4* q4 = (const float4*)(qptr + qq*32);
#pragma unroll
    for (int j = 0; j < 8; ++j){
      float4 u = q4[j];
      qv[4*j+0]=u.x; qv[4*j+1]=u.y; qv[4*j+2]=u.z; qv[4*j+3]=u.w;
    }
#pragma unroll
    for (int d = 0; d < 32; ++d) gp += qv[d]*w_gate[(qq*32+d)*3 + 0];
#pragma unroll
    for (int nn = 0; nn < 8; ++nn){
      int n = nn*4 + c;                       // c-rows 144 apart -> 2-way max
      const float4* kr = (const float4*)(Ks + n*RS + qq*QS);
      float p = 0.f;
#pragma unroll
      for (int j = 0; j < 8; ++j){
        float4 u = kr[j];
        p += qv[4*j+0]*u.x + qv[4*j+1]*u.y + qv[4*j+2]*u.z + qv[4*j+3]*u.w;
      }
      sc[nn] += p;
    }
  }
  float g0 = 1.f/(1.f + expf(-(gp + b_gate[0])));

  // ---- softmax across the 4 c-lanes (each holds 8 of 32 scores) ----
#pragma unroll
  for (int nn = 0; nn < 8; ++nn) sc[nn] *= SCALE;
  float m = sc[0];
#pragma unroll
  for (int nn = 1; nn < 8; ++nn) m = fmaxf(m, sc[nn]);
  m = fmaxf(m, __shfl_xor(m, 1)); m = fmaxf(m, __shfl_xor(m, 2));
  float l = 0.f;
#pragma unroll
  for (int nn = 0; nn < 8; ++nn){ sc[nn] = expf(sc[nn]-m); l += sc[nn]; }
  l += __shfl_xor(l, 1); l += __shfl_xor(l, 2);
  float inv = 1.f/l;
#pragma unroll
  for (int nn = 0; nn < 8; ++nn) Pl[qi*PLS + nn*4 + c] = sc[nn]*inv;
  __syncthreads();

  // ---- pooled P (sum over 64 queries; conflict-free via pad 33) ----
  if (tid < NBLK){
    float s = 0.f;
    for (int q2 = 0; q2 < 64; ++q2) s += Pl[q2*PLS + tid];
    pooled_part[(size_t)blk*NBLK + tid] = s;
  }

  // ---- PV (c owns dim-quarter; P broadcast from LDS) ----
  float o[32];
#pragma unroll
  for (int d = 0; d < 32; ++d) o[d] = 0.f;
  for (int n = 0; n < NBLK; ++n){
    float pb = Pl[qi*PLS + n];
    const float4* vr = (const float4*)(Vs + n*RS + c*QS);
#pragma unroll
    for (int j = 0; j < 8; ++j){
      float4 u = vr[j];
      o[4*j+0] += pb*u.x; o[4*j+1] += pb*u.y;
      o[4*j+2] += pb*u.z; o[4*j+3] += pb*u.w;
    }
  }
  float* op = out + ((size_t)row*QH + g*NH + h)*DIM + c*32;
#pragma unroll
  for (int d = 0; d < 32; ++d) op[d] = g0*o[d];   // overwrite (first branch)
}

// ---- kernel 2: h-merged role-split topk+slc | win attention (MFMA) ---------
// grid 256, 512 threads. block = (bbg, qb, role); wave w: head w&3, qhalf w>>2.
// One K/V stage per phase feeds 8 waves x 64 MFMA. Swapped QK^T:
// C[col=l15=query][row=quad*4+r=key] -> lane-local softmax.
// Layouts (m89/m91/m120): A[m=lane&15][k=quad*8+j], B[k=quad*8+j][n=lane&15],
// C[col=lane&15,row=quad*4+r]
__global__ __launch_bounds__(512, 2) void attn_k(
    const float* __restrict__ q, const ushort_t* __restrict__ Kb,
    const ushort_t* __restrict__ VT, const float* __restrict__ pp,
    const float* __restrict__ w_gate, const float* __restrict__ b_gate,
    float* __restrict__ slcbuf, float* __restrict__ out)
{
  int idx = blockIdx.x;             // 256 blocks
  int x = idx & 7, low = idx & 1, u = idx >> 3;
  int bbg = x >> 1;                 // (bb,g): same-bbg blocks share XCD pair
  int j = u*2 + low;                // 0..63
  int role = j >> 5;                // 0 = slc, 1 = win
  int qb = j & 31;
  int bb = bbg >> 1, g = bbg & 1;

  int tid = threadIdx.x;
  int lane = tid & 63, w = tid >> 6;        // wave 0..7
  int quad = lane >> 4, l15 = lane & 15;
  int h = w & 3, qh2 = w >> 2;              // head, query half
  int xr = (l15 & 7) << 4;                  // read-side XOR (matches prep_k)

  __shared__ ushort_t Ks[2][64*128];    // 32.0 KB (double buffer, linear+swz)
  __shared__ ushort_t VTs[2][128*64];   // 32.0 KB
  __shared__ ushort_t Ps[256*VP];       // 36.0 KB (per-wave 32-row slabs)
  __shared__ float gbuf[256];
  __shared__ int   idxs[NTOP];

  // ---- top-k (role 0 only; wave 0; lax.top_k tie rule) ----
  if (role == 0 && tid < 64){
    int n = lane;
    float val = -INFINITY;
    if (n < NBLK){
      const float* p0 = pp + ((size_t)((bb*KV+g)*NQB + qb)*NH)*NBLK + n;
      val = (p0[0] + p0[NBLK]) + (p0[2*NBLK] + p0[3*NBLK]);
    }
    for (int t = 0; t < NTOP; ++t){
      float bv = val; int bi = n;
      for (int mm = 1; mm < 32; mm <<= 1){
        float ov = __shfl_xor(bv, mm);
        int   oi = __shfl_xor(bi, mm);
        if (ov > bv || (ov == bv && oi < bi)){ bv = ov; bi = oi; }
      }
      if (lane == 0) idxs[t] = bi;
      if (n == bi) val = -INFINITY;
    }
  }

  // ---- Q fragments (pre-scaled by SCALE*log2e) + exact fp32 gate ----
  const float* qrow0 = q + ((size_t)(bb*SEQ + qb*64 + qh2*32 + l15)*QH + g*NH + h)*DIM;
  const float* qrow1 = qrow0 + (size_t)16*QH*DIM;
  int gcol = 1 + role;
  bf16x8 qfrag0[4], qfrag1[4];
  float gp0 = 0.f, gp1 = 0.f;
#pragma unroll
  for (int kc = 0; kc < 4; ++kc){
    int d0 = kc*32 + quad*8;
    float4 a0 = *(const float4*)(qrow0 + d0);
    float4 a1 = *(const float4*)(qrow0 + d0 + 4);
    float4 b0 = *(const float4*)(qrow1 + d0);
    float4 b1 = *(const float4*)(qrow1 + d0 + 4);
    float qa[8] = {a0.x,a0.y,a0.z,a0.w,a1.x,a1.y,a1.z,a1.w};
    float qc[8] = {b0.x,b0.y,b0.z,b0.w,b1.x,b1.y,b1.z,b1.w};
#pragma unroll
    for (int jj = 0; jj < 8; ++jj){
      float wg = w_gate[(d0+jj)*3 + gcol];
      gp0 += qa[jj]*wg; gp1 += qc[jj]*wg;
    }
    union { unsigned uu[4]; bf16x8 v8; } t0, t1;
#pragma unroll
    for (int p2 = 0; p2 < 4; ++p2){
      t0.uu[p2] = pkbf(qa[2*p2]*QSC, qa[2*p2+1]*QSC);
      t1.uu[p2] = pkbf(qc[2*p2]*QSC, qc[2*p2+1]*QSC);
    }
    qfrag0[kc] = t0.v8; qfrag1[kc] = t1.v8;
  }
  gp0 += __shfl_xor(gp0,16); gp0 += __shfl_xor(gp0,32);
  gp1 += __shfl_xor(gp1,16); gp1 += __shfl_xor(gp1,32);
  if (quad == 0){
    gbuf[w*32 + l15]      = 1.f/(1.f + __expf(-(gp0 + b_gate[gcol])));
    gbuf[w*32 + 16 + l15] = 1.f/(1.f + __expf(-(gp1 + b_gate[gcol])));
  }
  __syncthreads();   // publishes gbuf + idxs
  float gl0[4], gl1[4];
#pragma unroll
  for (int r = 0; r < 4; ++r){
    gl0[r] = gbuf[w*32 + quad*4 + r];
    gl1[r] = gbuf[w*32 + 16 + quad*4 + r];
  }

  const ushort_t* kbase  = Kb + (size_t)bbg*SEQ*DIM;
  const ushort_t* vtbase = VT + (size_t)bbg*DIM*SEQ;

  int kb0 = (qb >= 8) ? (qb - 8) : 0;
  int nph = (role == 0) ? NTOP : (qb - kb0 + 1);
  int qi0 = qh2*32 + l15, qi1 = qi0 + 16;   // lane-local query indices

  float m10 = -INFINITY, l10 = 0.f, m11 = -INFINITY, l11 = 0.f;
  f32x4 oacc0[8], oacc1[8];
  const f32x4 zero4 = {0.f,0.f,0.f,0.f};
#pragma unroll
  for (int dt = 0; dt < 8; ++dt){ oacc0[dt] = zero4; oacc1[dt] = zero4; }

  // staging: 512 threads x 2 units x 16B per tile; LDS dest linear
  // (wave-uniform base), global src per-lane & pre-swizzled by prep_k.
  auto stage = [&](int bufi, int kb_){
    const ushort_t* ksrc = kbase + (size_t)kb_*64*DIM;
#pragma unroll
    for (int jj = 0; jj < 2; ++jj)          // K tile: 1024 16B units
      async16(&Ks[bufi][(jj*512 + w*64)*8], ksrc + (size_t)(tid + jj*512)*8);
    const ushort_t* vsrc = vtbase + kb_*64;
#pragma unroll
    for (int jj = 0; jj < 2; ++jj){         // VT tile: [d=128][64]
      int i = tid + jj*512;
      int d = i >> 3, sg = i & 7;
      async16(&VTs[bufi][(jj*512 + w*64)*8], vsrc + (size_t)d*SEQ + sg*8);
    }
  };

  stage(0, (role == 0) ? idxs[0] : kb0);

  for (int t = 0; t < nph; ++t){
    int cur = t & 1;
    int kb = (role == 0) ? idxs[t] : (kb0 + t);
    // vmcnt(0)+lgkmcnt(0) drain + barrier: buf[cur] resident; buf[cur^1] free.
    __syncthreads();
    if (t+1 < nph){
      int kbn = (role == 0) ? idxs[t+1] : (kb0 + t + 1);
      stage(cur ^ 1, kbn);                  // flies under this phase
    }
    __builtin_amdgcn_sched_barrier(0);      // pin prefetch issue early

    // ---- QK^T swapped: mfma(K, Q); K A-frags shared across both q-tiles ----
    f32x4 sacc0[4], sacc1[4];
#pragma unroll
    for (int nt = 0; nt < 4; ++nt){ sacc0[nt] = zero4; sacc1[nt] = zero4; }
    __builtin_amdgcn_s_setprio(1);
#pragma unroll
    for (int kc = 0; kc < 4; ++kc){
#pragma unroll
      for (int nt = 0; nt < 4; ++nt){
        bf16x8 a = *(bf16x8*)((char*)&Ks[cur][0] + (nt*16 + l15)*256
                              + ((kc*64 + quad*16) ^ xr));
        sacc0[nt] = __builtin_amdgcn_mfma_f32_16x16x32_bf16(a, qfrag0[kc], sacc0[nt], 0, 0, 0);
        sacc1[nt] = __builtin_amdgcn_mfma_f32_16x16x32_bf16(a, qfrag1[kc], sacc1[nt], 0, 0, 0);
      }
    }
    __builtin_amdgcn_s_setprio(0);

    bool mlow  = (role == 1) && (kb == qb - 8);   // valid: key >= qi
    bool mhigh = (role == 1) && (kb == qb);       // valid: key <= qi
    bool domask = mlow | mhigh;

    // ---- lane-local softmax per q-tile (scores already in log2 domain) ----
    auto softmax_qt = [&](f32x4* sc, float& m1r, float& l1r, int qi_l,
                          bool& skipped) -> float {
      float mx = -INFINITY;
      if (domask){
#pragma unroll
        for (int nt = 0; nt < 4; ++nt)
#pragma unroll
          for (int r = 0; r < 4; ++r){
            int key = nt*16 + quad*4 + r;
            float sv = sc[nt][r];
            bool valid = (!mlow || key >= qi_l) && (!mhigh || key <= qi_l);
            sv = valid ? sv : -INFINITY;
            sc[nt][r] = sv;
            mx = fmaxf(mx, sv);
          }
      } else {
#pragma unroll
        for (int nt = 0; nt < 4; ++nt)
#pragma unroll
          for (int r = 0; r < 4; ++r) mx = fmaxf(mx, sc[nt][r]);
      }
      mx = fmaxf(mx, __shfl_xor(mx, 16));
      mx = fmaxf(mx, __shfl_xor(mx, 32));
      float al = 1.f;
      skipped = __all(mx <= m1r + 8.f);     // defer-max: P bounded by 2^8
      if (!skipped){
        float mn = fmaxf(m1r, mx);
        al = exp2f(m1r - mn);
        m1r = mn;
      }
      float s0 = 0.f;
#pragma unroll
      for (int nt = 0; nt < 4; ++nt)
#pragma unroll
        for (int r = 0; r < 4; ++r){
          float pe = exp2f(sc[nt][r] - m1r);   // masked -> 0
          sc[nt][r] = pe;
          s0 += pe;
        }
      s0 += __shfl_xor(s0, 16);
      s0 += __shfl_xor(s0, 32);
      l1r = l1r*al + s0;
      return al;
    };
    bool sk0, sk1;
    float al0 = softmax_qt(sacc0, m10, l10, qi0, sk0);
    float al1 = softmax_qt(sacc1, m11, l11, qi1, sk1);

    // ---- P -> LDS bf16, packed b64 (row = query; wave-private slab) ----
#pragma unroll
    for (int nt = 0; nt < 4; ++nt){
      uint2 p0, p1;
      p0.x = pkbf(sacc0[nt][0], sacc0[nt][1]);
      p0.y = pkbf(sacc0[nt][2], sacc0[nt][3]);
      p1.x = pkbf(sacc1[nt][0], sacc1[nt][1]);
      p1.y = pkbf(sacc1[nt][2], sacc1[nt][3]);
      *(uint2*)&Ps[(w*32 + l15)*VP + nt*16 + quad*4] = p0;
      *(uint2*)&Ps[(w*32 + 16 + l15)*VP + nt*16 + quad*4] = p1;
    }

    // ---- O rescale (skipped when defer-max held) ----
    if (!sk0){
      float ar[4];
#pragma unroll
      for (int r = 0; r < 4; ++r) ar[r] = __shfl(al0, quad*4 + r);
#pragma unroll
      for (int dt = 0; dt < 8; ++dt)
#pragma unroll
        for (int r = 0; r < 4; ++r) oacc0[dt][r] *= ar[r];
    }
    if (!sk1){
      float ar[4];
#pragma unroll
      for (int r = 0; r < 4; ++r) ar[r] = __shfl(al1, quad*4 + r);
#pragma unroll
      for (int dt = 0; dt < 8; ++dt)
#pragma unroll
        for (int r = 0; r < 4; ++r) oacc1[dt][r] *= ar[r];
    }

    // ---- PV: V B-frags shared across both q-tiles ----
#pragma unroll
    for (int kc2 = 0; kc2 < 2; ++kc2){
      bf16x8 pa0 = *(bf16x8*)&Ps[(w*32 + l15)*VP + kc2*32 + quad*8];
      bf16x8 pa1 = *(bf16x8*)&Ps[(w*32 + 16 + l15)*VP + kc2*32 + quad*8];
      __builtin_amdgcn_s_setprio(1);
#pragma unroll
      for (int dt = 0; dt < 8; ++dt){
        bf16x8 vb8 = *(bf16x8*)((char*)&VTs[cur][0] + (dt*16 + l15)*128
                                + ((kc2*64 + quad*16) ^ xr));
        oacc0[dt] = __builtin_amdgcn_mfma_f32_16x16x32_bf16(pa0, vb8, oacc0[dt], 0, 0, 0);
        oacc1[dt] = __builtin_amdgcn_mfma_f32_16x16x32_bf16(pa1, vb8, oacc1[dt], 0, 0, 0);
      }
      __builtin_amdgcn_s_setprio(0);
    }
  }

  // ---- epilogue: race-free plain stores ----
  float lr0[4], lr1[4];
#pragma unroll
  for (int r = 0; r < 4; ++r){
    lr0[r] = __shfl(l10, quad*4 + r);
    lr1[r] = __shfl(l11, quad*4 + r);
  }
#pragma unroll
  for (int r = 0; r < 4; ++r){
    float s20 = gl0[r] / lr0[r];
    float s21 = gl1[r] / lr1[r];
    size_t ob0 = ((size_t)(bb*SEQ + qb*64 + qh2*32 + quad*4 + r)*QH + g*NH + h)*DIM + l15;
    size_t ob1 = ob0 + (size_t)16*QH*DIM;
    if (role == 0){
      float* op0 = slcbuf + ob0;            // unique writer; full coverage
      float* op1 = slcbuf + ob1;
#pragma unroll
      for (int dt = 0; dt < 8; ++dt){
        op0[dt*16] = s20 * oacc0[dt][r];
        op1[dt*16] = s21 * oacc1[dt][r];
      }
    } else {
      float* op0 = out + ob0;               // unique writer; cmp already done
      float* op1 = out + ob1;
#pragma unroll
      for (int dt = 0; dt < 8; ++dt){
        op0[dt*16] += s20 * oacc0[dt][r];
        op1[dt*16] += s21 * oacc1[dt][r];
      }
    }
  }
}

// ---------------- kernel 3: merge (out += slcbuf) ---------------------------
__global__ __launch_bounds__(256) void merge_k(const float* __restrict__ slcbuf,
                                               float* __restrict__ out){
  int i = blockIdx.x * 256 + threadIdx.x;   // over 4096*8*128/4 float4s
  float4 a = ((const float4*)slcbuf)[i];
  float4 b = ((float4*)out)[i];
  b.x += a.x; b.y += a.y; b.z += a.z; b.w += a.w;
  ((float4*)out)[i] = b;
}

extern "C" void kernel_launch(void* const* d_in, const int* in_sizes, int n_in,
                              void* d_out, int out_size, void* d_ws, size_t ws_size,
                              hipStream_t stream) {
  const float* q      = (const float*)d_in[0];
  const float* k      = (const float*)d_in[1];
  const float* v      = (const float*)d_in[2];
  const float* w_k    = (const float*)d_in[3];
  const float* b_k    = (const float*)d_in[4];
  const float* w_v    = (const float*)d_in[5];
  const float* b_v    = (const float*)d_in[6];
  const float* w_gate = (const float*)d_in[7];
  const float* b_gate = (const float*)d_in[8];
  float* out = (float*)d_out;

  float* ws     = (float*)d_ws;
  float* Kc     = ws;                        // 16384 f32
  float* Vc     = ws + 16384;                // 16384 f32
  float* pp     = ws + 32768;                // 512*32 f32
  float* slcbuf = ws + 49152;                // 4.19M f32 (16.8 MB)
  ushort_t* Kb  = (ushort_t*)(ws + 4243456); // 4*2048*128 bf16 (2 MB)
  ushort_t* VT  = Kb + 1048576;              // 4*128*2048 bf16 (2 MB)

  prep_k    <<<256, 256, 0, stream>>>(k, v, w_k, b_k, w_v, b_v, Kb, VT, Kc, Vc);
  cmp_attn_k<<<NB*KV*NQB*NH, 256, 0, stream>>>(q, Kc, Vc, w_gate, b_gate, pp, out);
  attn_k    <<<256, 512, 0, stream>>>(q, Kb, VT, pp, w_gate, b_gate, slcbuf, out);
  merge_k   <<<4096, 256, 0, stream>>>(slcbuf, out);
}